// Round 9
// baseline (340.179 us; speedup 1.0000x reference)
//
#include <hip/hip_runtime.h>
#include <hip/hip_bf16.h>
#include <math.h>

typedef __bf16 bf16_t;
typedef __bf16 bf16x4 __attribute__((ext_vector_type(4)));
typedef __bf16 bf16x8 __attribute__((ext_vector_type(8)));
typedef float  f32x4  __attribute__((ext_vector_type(4)));
typedef float  f32x16 __attribute__((ext_vector_type(16)));

#define MFMA16(a,b,c) __builtin_amdgcn_mfma_f32_16x16x32_bf16((a),(b),(c),0,0,0)
#define MFMA32(a,b,c) __builtin_amdgcn_mfma_f32_32x32x16_bf16((a),(b),(c),0,0,0)

// Problem constants
#define B_ 2
#define L_ 2048
#define D_ 2048
#define H_ 16
#define KV_ 4
#define E_ 128
#define M_ (B_*L_)      // 4096 rows
#define NQKV_ 3072      // H*E + 2*KV*E

// async global->LDS 16B (m97 pattern; LDS dest is wave-uniform base + lane*16)
__device__ __forceinline__ void async_ld16(const bf16_t* g, bf16_t* l) {
    __builtin_amdgcn_global_load_lds((const __attribute__((address_space(1))) void*)g,
                                     (__attribute__((address_space(3))) void*)l, 16, 0, 0);
}

// ------------------- merged prep: x cast + qkv bias concat + weight transpose/cast
// (cast_bias and wtrans are independent and both memory-bound; one launch lets them
// co-run on the machine instead of serializing ~8µs + ~6µs)
__global__ __launch_bounds__(256) void prep_kernel(const float* __restrict__ src,
                                                   bf16_t* __restrict__ dst,
                                                   const float* __restrict__ bq,
                                                   const float* __restrict__ bk,
                                                   const float* __restrict__ bv,
                                                   float* __restrict__ qbias,
                                                   const float* __restrict__ Wq,
                                                   const float* __restrict__ Wk,
                                                   const float* __restrict__ Wv,
                                                   const float* __restrict__ Wo,
                                                   bf16_t* __restrict__ WqkvT,
                                                   bf16_t* __restrict__ WoT) {
    __shared__ float tile[32][33];
    int bid = blockIdx.x;
    if (bid < 8192) {
        int i = (bid * 256 + threadIdx.x) * 4;
        float4 v = *(const float4*)(src + i);
        bf16x4 o;
        o.x = (bf16_t)v.x; o.y = (bf16_t)v.y; o.z = (bf16_t)v.z; o.w = (bf16_t)v.w;
        *(bf16x4*)(dst + i) = o;
    } else if (bid < 8204) {
        int i = (bid - 8192) * 256 + threadIdx.x;
        if (i < 2048) qbias[i] = bq[i];
        else if (i < 2560) qbias[i] = bk[i - 2048];
        else if (i < 3072) qbias[i] = bv[i - 2560];
    } else {
        int g = bid - 8204;                 // 0..10239
        int bx = g % 160;
        int k0 = (g / 160) * 32;
        const float* W; bf16_t* WT; int N, n0;
        if (bx < 64)      { W = Wq; WT = WqkvT;                  N = 2048; n0 = bx * 32; }
        else if (bx < 80) { W = Wk; WT = WqkvT + 2048 * 2048;    N = 512;  n0 = (bx - 64) * 32; }
        else if (bx < 96) { W = Wv; WT = WqkvT + 2560 * 2048;    N = 512;  n0 = (bx - 80) * 32; }
        else              { W = Wo; WT = WoT;                    N = 2048; n0 = (bx - 96) * 32; }
        int tx = threadIdx.x & 31, ty = threadIdx.x >> 5;  // 32 x 8
        #pragma unroll
        for (int i = 0; i < 32; i += 8)
            tile[ty + i][tx] = W[(size_t)(k0 + ty + i) * N + n0 + tx];
        __syncthreads();
        #pragma unroll
        for (int i = 0; i < 32; i += 8)
            WT[(size_t)(n0 + ty + i) * 2048 + k0 + tx] = (bf16_t)tile[tx][ty + i];
    }
}

// ---------------------------------------------------------------- bf16 MFMA GEMM (128x128)
// BK=64 (R8: halves barrier rounds vs m97's 32 -- the ~72% stage/barrier overhead, m233).
// Both-sides XOR swizzle (rule #21): linear DMA dest, source chunk cl=cp^(r&7), read
// chunk (kk*4+quad)^(r&7) -> <=2-way conflicts (free). XCD bijective swizzle (T1).
// VSPLIT: QKV cols >=2560 (V) written transposed to Vt (replaces transpose_v kernel).
template <bool GELU, bool VSPLIT>
__global__ __launch_bounds__(256) void gemm_kernel(const bf16_t* __restrict__ A,
                                                   const bf16_t* __restrict__ BT,
                                                   const float* __restrict__ bias,
                                                   bf16_t* __restrict__ C,
                                                   bf16_t* __restrict__ Vt,
                                                   int M, int N, int K) {
    __shared__ __align__(16) bf16_t sA[128][64];
    __shared__ __align__(16) bf16_t sB[128][64];
    int tid = threadIdx.x;
    int wave = tid >> 6, lane = tid & 63;
    int l16 = lane & 15, quad = lane >> 4;
    int flat = blockIdx.y * gridDim.x + blockIdx.x;
    int cpx = (gridDim.x * gridDim.y) >> 3;
    int swz = (flat & 7) * cpx + (flat >> 3);
    int col0 = (swz % gridDim.x) * 128;
    int row0 = (swz / gridDim.x) * 128;
    int wm = (wave >> 1) * 64;
    int wn = (wave & 1) * 64;

    f32x4 acc[4][4];
    #pragma unroll
    for (int i = 0; i < 4; ++i)
        #pragma unroll
        for (int j = 0; j < 4; ++j)
            acc[i][j] = f32x4{0.f, 0.f, 0.f, 0.f};

    for (int k0 = 0; k0 < K; k0 += 64) {
        #pragma unroll
        for (int c = 0; c < 4; ++c) {
            int ch = c * 256 + tid;
            int r = ch >> 3, cp = ch & 7;
            int cl = cp ^ (r & 7);
            async_ld16(&A[(size_t)(row0 + r) * K + k0 + cl * 8], &sA[r][cp * 8]);
            async_ld16(&BT[(size_t)(col0 + r) * K + k0 + cl * 8], &sB[r][cp * 8]);
        }
        __syncthreads();
        #pragma unroll
        for (int kk = 0; kk < 2; ++kk) {
            bf16x8 af[4], bf[4];
            #pragma unroll
            for (int mt = 0; mt < 4; ++mt) {
                int r = wm + mt * 16 + l16;
                af[mt] = *(const bf16x8*)&sA[r][((kk * 4 + quad) ^ (r & 7)) * 8];
            }
            #pragma unroll
            for (int nt = 0; nt < 4; ++nt) {
                int r = wn + nt * 16 + l16;
                bf[nt] = *(const bf16x8*)&sB[r][((kk * 4 + quad) ^ (r & 7)) * 8];
            }
            #pragma unroll
            for (int mt = 0; mt < 4; ++mt)
                #pragma unroll
                for (int nt = 0; nt < 4; ++nt)
                    acc[mt][nt] = MFMA16(af[mt], bf[nt], acc[mt][nt]);
        }
        __syncthreads();
    }

    #pragma unroll
    for (int mt = 0; mt < 4; ++mt) {
        #pragma unroll
        for (int nt = 0; nt < 4; ++nt) {
            int gcol = col0 + wn + nt * 16 + l16;
            float bv = bias[gcol];
            float vv[4];
            #pragma unroll
            for (int r = 0; r < 4; ++r) {
                float v = acc[mt][nt][r] + bv;
                if (GELU) v = 0.5f * v * (1.f + erff(v * 0.70710678118654752f));
                vv[r] = v;
            }
            int grow0 = row0 + wm + mt * 16 + quad * 4;   // 4-aligned
            if (VSPLIT && gcol >= 2560) {
                int b = grow0 >> 11, l = grow0 & 2047;
                bf16x4 ov;
                #pragma unroll
                for (int r = 0; r < 4; ++r) ov[r] = (bf16_t)vv[r];
                *(bf16x4*)&Vt[((size_t)(b * 512) + (gcol - 2560)) * L_ + l] = ov;
            } else {
                #pragma unroll
                for (int r = 0; r < 4; ++r)
                    C[(size_t)(grow0 + r) * N + gcol] = (bf16_t)vv[r];
            }
        }
    }
}

// ---------------------------------------------------------------- flash attention (causal GQA)
// R6 structure. NEW (T12 primitive): PV B-frag half-exchange via v_permlane32_swap_b32
// (2/kc) instead of 2x shfl_xor(ds_bpermute) + send/keep/lo/hi selects -- verified
// algebraically: for d=pk[g0], s=pk[g0+1], swap leaves half0 lanes with (own pk[g0],
// partner pk[g0]) and half1 with (partner pk[g0+1], own pk[g0+1]) == current pf exactly
// (lane q <-> 32+q pairing preserved). Also: l_i keeps own-half partial, cross-half
// reduce deferred to epilogue (sum associative) -- one shfl per block, not per iter.
__global__ __launch_bounds__(128, 2) void attn_kernel(const bf16_t* __restrict__ QKV,
                                                      const bf16_t* __restrict__ Vt,
                                                      bf16_t* __restrict__ Ctx) {
    __shared__ __align__(16) bf16_t sK[2][64][128];    // [buf][kpos][e], chunk ^= kpos&15

    const int tid = threadIdx.x;                // 0..127
    const int wave = tid >> 6, lane = tid & 63;
    const int l31 = lane & 31, half = lane >> 5;

    const int idx = blockIdx.x;
    const int rr = idx >> 5;                    // 0..31
    const int bh = idx & 31;                    // b*16 + h
    const int u = (rr < 8) ? 31 - rr : (rr < 16) ? rr - 8 : (rr < 24) ? 39 - rr : rr - 16;
    const int h = bh & 15, b = bh >> 4;
    const int kv = h & 3;

    const bf16_t* Kbase = QKV + (size_t)b * L_ * NQKV_ + 2048 + kv * 128;
    const bf16_t* Vbase = Vt + (size_t)(b * 4 + kv) * 128 * L_;
    const float SC = 0.12754995f;               // (1/sqrt(128)) * log2(e)

    const int qrow = u * 64 + wave * 32 + l31;

    bf16x8 qf[8];
    const bf16_t* Qrow = QKV + (size_t)(b * L_ + qrow) * NQKV_ + h * 128 + half * 8;
    #pragma unroll
    for (int et = 0; et < 8; ++et) qf[et] = *(const bf16x8*)&Qrow[et * 16];

    f32x16 acc[4];
    #pragma unroll
    for (int em = 0; em < 4; ++em)
        #pragma unroll
        for (int j = 0; j < 16; ++j) acc[em][j] = 0.f;
    float l_i = 0.f;   // own-half partial; cross-half combined in epilogue

    #define STAGE_K(KT, BUF)                                                          \
        {                                                                             \
            int kk = (KT) * 64;                                                       \
            _Pragma("unroll")                                                         \
            for (int rep = 0; rep < 8; ++rep) {                                       \
                int ch = rep * 128 + tid;                                             \
                int rk = ch >> 4;                                                     \
                int sc = (ch & 15) ^ (rk & 15);                                       \
                async_ld16(&Kbase[(size_t)(kk + rk) * NQKV_ + sc * 8],                \
                           ((bf16_t*)sK[BUF]) + (size_t)ch * 8);                      \
            }                                                                         \
        }

    STAGE_K(0, 0);
    __syncthreads();

    for (int kt = 0; kt <= u; ++kt) {
        const int bufi = kt & 1;
        if (kt < u) STAGE_K(kt + 1, bufi ^ 1);

        bf16x8 vr[16];
        #pragma unroll
        for (int kc = 0; kc < 4; ++kc)
            #pragma unroll
            for (int em = 0; em < 4; ++em)
                vr[kc * 4 + em] = *(const bf16x8*)&Vbase[(size_t)(em * 32 + l31) * L_ +
                                                         kt * 64 + (kc * 2 + half) * 8];

        f32x16 s[2];
        #pragma unroll
        for (int mt = 0; mt < 2; ++mt)
            #pragma unroll
            for (int j = 0; j < 16; ++j) s[mt][j] = 0.f;
        __builtin_amdgcn_s_setprio(1);
        #pragma unroll
        for (int mt = 0; mt < 2; ++mt)
            #pragma unroll
            for (int et = 0; et < 8; ++et) {
                bf16x8 kf = *(const bf16x8*)&sK[bufi][mt * 32 + l31][((et * 2 + half) ^ (l31 & 15)) * 8];
                s[mt] = MFMA32(kf, qf[et], s[mt]);
            }
        __builtin_amdgcn_s_setprio(0);

        if (kt == u) {
            #pragma unroll
            for (int mt = 0; mt < 2; ++mt)
                #pragma unroll
                for (int j = 0; j < 16; ++j) {
                    int kidx = kt * 64 + mt * 32 + (j & 3) + 8 * (j >> 2) + 4 * half;
                    if (kidx > qrow) s[mt][j] = -3.0e38f;
                }
        }

        // static-max softmax: P = exp2(s*SC); own-half running sum only
        float rs = 0.f;
        #pragma unroll
        for (int mt = 0; mt < 2; ++mt)
            #pragma unroll
            for (int j = 0; j < 16; ++j) {
                float p = exp2f(s[mt][j] * SC);
                s[mt][j] = p;
                rs += p;
            }
        l_i += rs;

        // pack P to bf16 groups: pk[mt][g] holds kpos = 32mt+8g+4*half+(0..3), q=l31
        bf16x4 pk[2][4];
        #pragma unroll
        for (int mt = 0; mt < 2; ++mt)
            #pragma unroll
            for (int g = 0; g < 4; ++g) {
                bf16x4 tt;
                #pragma unroll
                for (int i = 0; i < 4; ++i) tt[i] = (bf16_t)s[mt][g * 4 + i];
                pk[mt][g] = tt;
            }

        // ctx^T += V^T @ P : B-frag for kc needs kpos 16kc+8*half+(0..7). Half-exchange
        // via permlane32_swap: d'=(d_lo, s_lo-from-partner), s'=(d_hi-from-partner, s_hi)
        // -> d' is the lo word-pair and s' the hi word-pair for BOTH halves.
        #pragma unroll
        for (int kc = 0; kc < 4; ++kc) {
            const int mts = kc >> 1, g0 = 2 * (kc & 1);
            union { bf16x4 v; int i[2]; } a, bb;
            a.v = pk[mts][g0];
            bb.v = pk[mts][g0 + 1];
            asm("v_permlane32_swap_b32 %0, %1" : "+v"(a.i[0]), "+v"(bb.i[0]));
            asm("v_permlane32_swap_b32 %0, %1" : "+v"(a.i[1]), "+v"(bb.i[1]));
            bf16x8 pf = __builtin_shufflevector(a.v, bb.v, 0, 1, 2, 3, 4, 5, 6, 7);
            __builtin_amdgcn_s_setprio(1);
            #pragma unroll
            for (int em = 0; em < 4; ++em)
                acc[em] = MFMA32(vr[kc * 4 + em], pf, acc[em]);
            __builtin_amdgcn_s_setprio(0);
        }

        __syncthreads();
    }

    l_i += __shfl_xor(l_i, 32, 64);   // combine halves once
    const float inv = 1.f / l_i;
    bf16_t* Cp = Ctx + (size_t)(b * L_ + qrow) * 2048 + h * 128;
    #pragma unroll
    for (int em = 0; em < 4; ++em)
        #pragma unroll
        for (int g = 0; g < 4; ++g) {
            bf16x4 ov;
            #pragma unroll
            for (int i = 0; i < 4; ++i) ov[i] = (bf16_t)(acc[em][g * 4 + i] * inv);
            *(bf16x4*)&Cp[em * 32 + g * 8 + half * 4] = ov;
        }
}

// ------------------------------------------ residual + LayerNorm (GELU already fused in GEMM)
__global__ __launch_bounds__(256) void ln_kernel(const bf16_t* __restrict__ Y,
                                                 const float* __restrict__ X,
                                                 const float* __restrict__ gamma,
                                                 const float* __restrict__ beta,
                                                 float* __restrict__ out) {
    __shared__ float sr[2048];
    __shared__ float wred[8];
    size_t row = blockIdx.x;
    const bf16_t* y = Y + row * 2048;
    const float* x = X + row * 2048;
    float sum = 0.f, ssq = 0.f;
    #pragma unroll
    for (int c = 0; c < 2; ++c) {
        int i = (c * 256 + threadIdx.x) * 4;
        bf16x4 yv = *(const bf16x4*)(y + i);
        float4 xv = *(const float4*)(x + i);
        float r0 = xv.x + (float)yv[0];
        float r1 = xv.y + (float)yv[1];
        float r2 = xv.z + (float)yv[2];
        float r3 = xv.w + (float)yv[3];
        sr[i] = r0; sr[i + 1] = r1; sr[i + 2] = r2; sr[i + 3] = r3;
        sum += r0 + r1 + r2 + r3;
        ssq += r0 * r0 + r1 * r1 + r2 * r2 + r3 * r3;
    }
    #pragma unroll
    for (int off = 32; off > 0; off >>= 1) {
        sum += __shfl_xor(sum, off, 64);
        ssq += __shfl_xor(ssq, off, 64);
    }
    int wv = threadIdx.x >> 6;
    if ((threadIdx.x & 63) == 0) { wred[wv] = sum; wred[wv + 4] = ssq; }
    __syncthreads();
    sum = wred[0] + wred[1] + wred[2] + wred[3];
    ssq = wred[4] + wred[5] + wred[6] + wred[7];
    float mu = sum * (1.f / 2048.f);
    float var = ssq * (1.f / 2048.f) - mu * mu;
    float rstd = rsqrtf(var + 1e-5f);
    #pragma unroll
    for (int c = 0; c < 2; ++c) {
        int i = (c * 256 + threadIdx.x) * 4;
        float4 gv = *(const float4*)(gamma + i);
        float4 bv = *(const float4*)(beta + i);
        float4 o;
        o.x = (sr[i]     - mu) * rstd * gv.x + bv.x;
        o.y = (sr[i + 1] - mu) * rstd * gv.y + bv.y;
        o.z = (sr[i + 2] - mu) * rstd * gv.z + bv.z;
        o.w = (sr[i + 3] - mu) * rstd * gv.w + bv.w;
        *(float4*)(out + row * 2048 + i) = o;
    }
}

// ----------------------------------------------------------------------------- launch
extern "C" void kernel_launch(void* const* d_in, const int* in_sizes, int n_in,
                              void* d_out, int out_size, void* d_ws, size_t ws_size,
                              hipStream_t stream) {
    const float* x     = (const float*)d_in[0];
    const float* Wq    = (const float*)d_in[1];
    const float* bq    = (const float*)d_in[2];
    const float* Wk    = (const float*)d_in[3];
    const float* bk    = (const float*)d_in[4];
    const float* Wv    = (const float*)d_in[5];
    const float* bv    = (const float*)d_in[6];
    const float* Wo    = (const float*)d_in[7];
    const float* bo    = (const float*)d_in[8];
    const float* gamma = (const float*)d_in[9];
    const float* beta  = (const float*)d_in[10];
    float* out = (float*)d_out;

    char* ws = (char*)d_ws;
    size_t off = 0;
    bf16_t* xb    = (bf16_t*)(ws + off); off += 16777216;   // 4096x2048 bf16
    bf16_t* WqkvT = (bf16_t*)(ws + off); off += 12582912;   // 3072x2048 bf16
    bf16_t* WoT   = (bf16_t*)(ws + off); off += 8388608;    // 2048x2048 bf16
    float*  qbias = (float*)(ws + off);  off += 12288;      // 3072 f32
    bf16_t* QKV   = (bf16_t*)(ws + off); off += 25165824;   // 4096x3072 bf16 (V third unused)
    bf16_t* Vt    = (bf16_t*)(ws + off); off += 4194304;    // 8x128x2048 bf16
    bf16_t* Cb    = (bf16_t*)(ws + off); off += 16777216;   // 4096x2048 bf16
    bf16_t* Yb    = (bf16_t*)(ws + off); off += 16777216;   // 4096x2048 bf16 (GELU'd)

    prep_kernel<<<18444, 256, 0, stream>>>(x, xb, bq, bk, bv, qbias,
                                           Wq, Wk, Wv, Wo, WqkvT, WoT);

    // QKV GEMM (BK=64): writes Q,K to QKV and V transposed to Vt
    gemm_kernel<false, true><<<dim3(24, 32), 256, 0, stream>>>(xb, WqkvT, qbias, QKV, Vt, M_, NQKV_, D_);
    attn_kernel<<<1024, 128, 0, stream>>>(QKV, Vt, Cb);
    gemm_kernel<true, false><<<dim3(16, 32), 256, 0, stream>>>(Cb, WoT, bo, Yb, nullptr, M_, D_, 2048);
    ln_kernel<<<M_, 256, 0, stream>>>(Yb, x, gamma, beta, out);
}

// Round 13
// 329.169 us; speedup vs baseline: 1.0334x; 1.0334x over previous
//
#include <hip/hip_runtime.h>
#include <hip/hip_bf16.h>
#include <math.h>

typedef __bf16 bf16_t;
typedef __bf16 bf16x4 __attribute__((ext_vector_type(4)));
typedef __bf16 bf16x8 __attribute__((ext_vector_type(8)));
typedef float  f32x4  __attribute__((ext_vector_type(4)));
typedef float  f32x16 __attribute__((ext_vector_type(16)));

#define MFMA16(a,b,c) __builtin_amdgcn_mfma_f32_16x16x32_bf16((a),(b),(c),0,0,0)
#define MFMA32(a,b,c) __builtin_amdgcn_mfma_f32_32x32x16_bf16((a),(b),(c),0,0,0)

// Problem constants
#define B_ 2
#define L_ 2048
#define D_ 2048
#define H_ 16
#define KV_ 4
#define E_ 128
#define M_ (B_*L_)      // 4096 rows
#define NQKV_ 3072      // H*E + 2*KV*E

// async global->LDS 16B (m97 pattern; LDS dest is wave-uniform base + lane*16)
__device__ __forceinline__ void async_ld16(const bf16_t* g, bf16_t* l) {
    __builtin_amdgcn_global_load_lds((const __attribute__((address_space(1))) void*)g,
                                     (__attribute__((address_space(3))) void*)l, 16, 0, 0);
}

// ------------------- merged prep: x cast + qkv bias concat + weight transpose/cast
__global__ __launch_bounds__(256) void prep_kernel(const float* __restrict__ src,
                                                   bf16_t* __restrict__ dst,
                                                   const float* __restrict__ bq,
                                                   const float* __restrict__ bk,
                                                   const float* __restrict__ bv,
                                                   float* __restrict__ qbias,
                                                   const float* __restrict__ Wq,
                                                   const float* __restrict__ Wk,
                                                   const float* __restrict__ Wv,
                                                   const float* __restrict__ Wo,
                                                   bf16_t* __restrict__ WqkvT,
                                                   bf16_t* __restrict__ WoT) {
    __shared__ float tile[32][33];
    int bid = blockIdx.x;
    if (bid < 8192) {
        int i = (bid * 256 + threadIdx.x) * 4;
        float4 v = *(const float4*)(src + i);
        bf16x4 o;
        o.x = (bf16_t)v.x; o.y = (bf16_t)v.y; o.z = (bf16_t)v.z; o.w = (bf16_t)v.w;
        *(bf16x4*)(dst + i) = o;
    } else if (bid < 8204) {
        int i = (bid - 8192) * 256 + threadIdx.x;
        if (i < 2048) qbias[i] = bq[i];
        else if (i < 2560) qbias[i] = bk[i - 2048];
        else if (i < 3072) qbias[i] = bv[i - 2560];
    } else {
        int g = bid - 8204;                 // 0..10239
        int bx = g % 160;
        int k0 = (g / 160) * 32;
        const float* W; bf16_t* WT; int N, n0;
        if (bx < 64)      { W = Wq; WT = WqkvT;                  N = 2048; n0 = bx * 32; }
        else if (bx < 80) { W = Wk; WT = WqkvT + 2048 * 2048;    N = 512;  n0 = (bx - 64) * 32; }
        else if (bx < 96) { W = Wv; WT = WqkvT + 2560 * 2048;    N = 512;  n0 = (bx - 80) * 32; }
        else              { W = Wo; WT = WoT;                    N = 2048; n0 = (bx - 96) * 32; }
        int tx = threadIdx.x & 31, ty = threadIdx.x >> 5;  // 32 x 8
        #pragma unroll
        for (int i = 0; i < 32; i += 8)
            tile[ty + i][tx] = W[(size_t)(k0 + ty + i) * N + n0 + tx];
        __syncthreads();
        #pragma unroll
        for (int i = 0; i < 32; i += 8)
            WT[(size_t)(n0 + ty + i) * 2048 + k0 + tx] = (bf16_t)tile[tx][ty + i];
    }
}

// ---------------------------------------------------------------- bf16 MFMA GEMM (128x128)
// BK=64 (R8), both-sides XOR swizzle, XCD bijective swizzle, VSPLIT V-transpose epilogue.
template <bool GELU, bool VSPLIT>
__global__ __launch_bounds__(256) void gemm_kernel(const bf16_t* __restrict__ A,
                                                   const bf16_t* __restrict__ BT,
                                                   const float* __restrict__ bias,
                                                   bf16_t* __restrict__ C,
                                                   bf16_t* __restrict__ Vt,
                                                   int M, int N, int K) {
    __shared__ __align__(16) bf16_t sA[128][64];
    __shared__ __align__(16) bf16_t sB[128][64];
    int tid = threadIdx.x;
    int wave = tid >> 6, lane = tid & 63;
    int l16 = lane & 15, quad = lane >> 4;
    int flat = blockIdx.y * gridDim.x + blockIdx.x;
    int cpx = (gridDim.x * gridDim.y) >> 3;
    int swz = (flat & 7) * cpx + (flat >> 3);
    int col0 = (swz % gridDim.x) * 128;
    int row0 = (swz / gridDim.x) * 128;
    int wm = (wave >> 1) * 64;
    int wn = (wave & 1) * 64;

    f32x4 acc[4][4];
    #pragma unroll
    for (int i = 0; i < 4; ++i)
        #pragma unroll
        for (int j = 0; j < 4; ++j)
            acc[i][j] = f32x4{0.f, 0.f, 0.f, 0.f};

    for (int k0 = 0; k0 < K; k0 += 64) {
        #pragma unroll
        for (int c = 0; c < 4; ++c) {
            int ch = c * 256 + tid;
            int r = ch >> 3, cp = ch & 7;
            int cl = cp ^ (r & 7);
            async_ld16(&A[(size_t)(row0 + r) * K + k0 + cl * 8], &sA[r][cp * 8]);
            async_ld16(&BT[(size_t)(col0 + r) * K + k0 + cl * 8], &sB[r][cp * 8]);
        }
        __syncthreads();
        #pragma unroll
        for (int kk = 0; kk < 2; ++kk) {
            bf16x8 af[4], bf[4];
            #pragma unroll
            for (int mt = 0; mt < 4; ++mt) {
                int r = wm + mt * 16 + l16;
                af[mt] = *(const bf16x8*)&sA[r][((kk * 4 + quad) ^ (r & 7)) * 8];
            }
            #pragma unroll
            for (int nt = 0; nt < 4; ++nt) {
                int r = wn + nt * 16 + l16;
                bf[nt] = *(const bf16x8*)&sB[r][((kk * 4 + quad) ^ (r & 7)) * 8];
            }
            #pragma unroll
            for (int mt = 0; mt < 4; ++mt)
                #pragma unroll
                for (int nt = 0; nt < 4; ++nt)
                    acc[mt][nt] = MFMA16(af[mt], bf[nt], acc[mt][nt]);
        }
        __syncthreads();
    }

    #pragma unroll
    for (int mt = 0; mt < 4; ++mt) {
        #pragma unroll
        for (int nt = 0; nt < 4; ++nt) {
            int gcol = col0 + wn + nt * 16 + l16;
            float bv = bias[gcol];
            float vv[4];
            #pragma unroll
            for (int r = 0; r < 4; ++r) {
                float v = acc[mt][nt][r] + bv;
                if (GELU) v = 0.5f * v * (1.f + erff(v * 0.70710678118654752f));
                vv[r] = v;
            }
            int grow0 = row0 + wm + mt * 16 + quad * 4;   // 4-aligned
            if (VSPLIT && gcol >= 2560) {
                int b = grow0 >> 11, l = grow0 & 2047;
                bf16x4 ov;
                #pragma unroll
                for (int r = 0; r < 4; ++r) ov[r] = (bf16_t)vv[r];
                *(bf16x4*)&Vt[((size_t)(b * 512) + (gcol - 2560)) * L_ + l] = ov;
            } else {
                #pragma unroll
                for (int r = 0; r < 4; ++r)
                    C[(size_t)(grow0 + r) * N + gcol] = (bf16_t)vv[r];
            }
        }
    }
}

// ---------------------------------------------------------------- flash attention (causal GQA)
// R9 PROVEN KERNEL (last passing attn, 340.2 us total). 2-wave 64-row q-tile blocks,
// bijective 4-phase u-map, K via global_load_lds DMA with swizzle involution +
// __syncthreads per iter (drains DMA, guards double buffer -- correct by construction),
// V direct from L2 with deep prefetch, static-max softmax, permlane32_swap half-exchange,
// l cross-half reduce deferred to epilogue.
// NOTE (R10-R12 post-mortem): barrier-free 1-wave + counted-vmcnt variants failed
// DETERMINISTICALLY (identical absmax across sync variants) -- counted vmcnt windows
// mixing global_load (->VGPR) and global_load_lds (->LDS) are NOT verified to retire
// in relative order on gfx950; do not mix op types in one counted drain.
__global__ __launch_bounds__(128, 2) void attn_kernel(const bf16_t* __restrict__ QKV,
                                                      const bf16_t* __restrict__ Vt,
                                                      bf16_t* __restrict__ Ctx) {
    __shared__ __align__(16) bf16_t sK[2][64][128];    // [buf][kpos][e], chunk ^= kpos&15

    const int tid = threadIdx.x;                // 0..127
    const int wave = tid >> 6, lane = tid & 63;
    const int l31 = lane & 31, half = lane >> 5;

    const int idx = blockIdx.x;
    const int rr = idx >> 5;                    // 0..31
    const int bh = idx & 31;                    // b*16 + h
    const int u = (rr < 8) ? 31 - rr : (rr < 16) ? rr - 8 : (rr < 24) ? 39 - rr : rr - 16;
    const int h = bh & 15, b = bh >> 4;
    const int kv = h & 3;

    const bf16_t* Kbase = QKV + (size_t)b * L_ * NQKV_ + 2048 + kv * 128;
    const bf16_t* Vbase = Vt + (size_t)(b * 4 + kv) * 128 * L_;
    const float SC = 0.12754995f;               // (1/sqrt(128)) * log2(e)

    const int qrow = u * 64 + wave * 32 + l31;

    bf16x8 qf[8];
    const bf16_t* Qrow = QKV + (size_t)(b * L_ + qrow) * NQKV_ + h * 128 + half * 8;
    #pragma unroll
    for (int et = 0; et < 8; ++et) qf[et] = *(const bf16x8*)&Qrow[et * 16];

    f32x16 acc[4];
    #pragma unroll
    for (int em = 0; em < 4; ++em)
        #pragma unroll
        for (int j = 0; j < 16; ++j) acc[em][j] = 0.f;
    float l_i = 0.f;   // own-half partial; cross-half combined in epilogue

    #define STAGE_K(KT, BUF)                                                          \
        {                                                                             \
            int kk = (KT) * 64;                                                       \
            _Pragma("unroll")                                                         \
            for (int rep = 0; rep < 8; ++rep) {                                       \
                int ch = rep * 128 + tid;                                             \
                int rk = ch >> 4;                                                     \
                int sc = (ch & 15) ^ (rk & 15);                                       \
                async_ld16(&Kbase[(size_t)(kk + rk) * NQKV_ + sc * 8],                \
                           ((bf16_t*)sK[BUF]) + (size_t)ch * 8);                      \
            }                                                                         \
        }

    STAGE_K(0, 0);
    __syncthreads();

    for (int kt = 0; kt <= u; ++kt) {
        const int bufi = kt & 1;
        if (kt < u) STAGE_K(kt + 1, bufi ^ 1);

        bf16x8 vr[16];
        #pragma unroll
        for (int kc = 0; kc < 4; ++kc)
            #pragma unroll
            for (int em = 0; em < 4; ++em)
                vr[kc * 4 + em] = *(const bf16x8*)&Vbase[(size_t)(em * 32 + l31) * L_ +
                                                         kt * 64 + (kc * 2 + half) * 8];

        f32x16 s[2];
        #pragma unroll
        for (int mt = 0; mt < 2; ++mt)
            #pragma unroll
            for (int j = 0; j < 16; ++j) s[mt][j] = 0.f;
        __builtin_amdgcn_s_setprio(1);
        #pragma unroll
        for (int mt = 0; mt < 2; ++mt)
            #pragma unroll
            for (int et = 0; et < 8; ++et) {
                bf16x8 kf = *(const bf16x8*)&sK[bufi][mt * 32 + l31][((et * 2 + half) ^ (l31 & 15)) * 8];
                s[mt] = MFMA32(kf, qf[et], s[mt]);
            }
        __builtin_amdgcn_s_setprio(0);

        if (kt == u) {
            #pragma unroll
            for (int mt = 0; mt < 2; ++mt)
                #pragma unroll
                for (int j = 0; j < 16; ++j) {
                    int kidx = kt * 64 + mt * 32 + (j & 3) + 8 * (j >> 2) + 4 * half;
                    if (kidx > qrow) s[mt][j] = -3.0e38f;
                }
        }

        // static-max softmax: P = exp2(s*SC); own-half running sum only
        float rs = 0.f;
        #pragma unroll
        for (int mt = 0; mt < 2; ++mt)
            #pragma unroll
            for (int j = 0; j < 16; ++j) {
                float p = exp2f(s[mt][j] * SC);
                s[mt][j] = p;
                rs += p;
            }
        l_i += rs;

        // pack P to bf16 groups: pk[mt][g] holds kpos = 32mt+8g+4*half+(0..3), q=l31
        bf16x4 pk[2][4];
        #pragma unroll
        for (int mt = 0; mt < 2; ++mt)
            #pragma unroll
            for (int g = 0; g < 4; ++g) {
                bf16x4 tt;
                #pragma unroll
                for (int i = 0; i < 4; ++i) tt[i] = (bf16_t)s[mt][g * 4 + i];
                pk[mt][g] = tt;
            }

        // ctx^T += V^T @ P : permlane32_swap half-exchange (proven R9 algebra)
        #pragma unroll
        for (int kc = 0; kc < 4; ++kc) {
            const int mts = kc >> 1, g0 = 2 * (kc & 1);
            union { bf16x4 v; int i[2]; } a, bb;
            a.v = pk[mts][g0];
            bb.v = pk[mts][g0 + 1];
            asm("v_permlane32_swap_b32 %0, %1" : "+v"(a.i[0]), "+v"(bb.i[0]));
            asm("v_permlane32_swap_b32 %0, %1" : "+v"(a.i[1]), "+v"(bb.i[1]));
            bf16x8 pf = __builtin_shufflevector(a.v, bb.v, 0, 1, 2, 3, 4, 5, 6, 7);
            __builtin_amdgcn_s_setprio(1);
            #pragma unroll
            for (int em = 0; em < 4; ++em)
                acc[em] = MFMA32(vr[kc * 4 + em], pf, acc[em]);
            __builtin_amdgcn_s_setprio(0);
        }

        __syncthreads();
    }

    l_i += __shfl_xor(l_i, 32, 64);   // combine halves once
    const float inv = 1.f / l_i;
    bf16_t* Cp = Ctx + (size_t)(b * L_ + qrow) * 2048 + h * 128;
    #pragma unroll
    for (int em = 0; em < 4; ++em)
        #pragma unroll
        for (int g = 0; g < 4; ++g) {
            bf16x4 ov;
            #pragma unroll
            for (int i = 0; i < 4; ++i) ov[i] = (bf16_t)(acc[em][g * 4 + i] * inv);
            *(bf16x4*)&Cp[em * 32 + g * 8 + half * 4] = ov;
        }
}

// ------------------------------------------ residual + LayerNorm (GELU already fused in GEMM)
__global__ __launch_bounds__(256) void ln_kernel(const bf16_t* __restrict__ Y,
                                                 const float* __restrict__ X,
                                                 const float* __restrict__ gamma,
                                                 const float* __restrict__ beta,
                                                 float* __restrict__ out) {
    __shared__ float sr[2048];
    __shared__ float wred[8];
    size_t row = blockIdx.x;
    const bf16_t* y = Y + row * 2048;
    const float* x = X + row * 2048;
    float sum = 0.f, ssq = 0.f;
    #pragma unroll
    for (int c = 0; c < 2; ++c) {
        int i = (c * 256 + threadIdx.x) * 4;
        bf16x4 yv = *(const bf16x4*)(y + i);
        float4 xv = *(const float4*)(x + i);
        float r0 = xv.x + (float)yv[0];
        float r1 = xv.y + (float)yv[1];
        float r2 = xv.z + (float)yv[2];
        float r3 = xv.w + (float)yv[3];
        sr[i] = r0; sr[i + 1] = r1; sr[i + 2] = r2; sr[i + 3] = r3;
        sum += r0 + r1 + r2 + r3;
        ssq += r0 * r0 + r1 * r1 + r2 * r2 + r3 * r3;
    }
    #pragma unroll
    for (int off = 32; off > 0; off >>= 1) {
        sum += __shfl_xor(sum, off, 64);
        ssq += __shfl_xor(ssq, off, 64);
    }
    int wv = threadIdx.x >> 6;
    if ((threadIdx.x & 63) == 0) { wred[wv] = sum; wred[wv + 4] = ssq; }
    __syncthreads();
    sum = wred[0] + wred[1] + wred[2] + wred[3];
    ssq = wred[4] + wred[5] + wred[6] + wred[7];
    float mu = sum * (1.f / 2048.f);
    float var = ssq * (1.f / 2048.f) - mu * mu;
    float rstd = rsqrtf(var + 1e-5f);
    #pragma unroll
    for (int c = 0; c < 2; ++c) {
        int i = (c * 256 + threadIdx.x) * 4;
        float4 gv = *(const float4*)(gamma + i);
        float4 bv = *(const float4*)(beta + i);
        float4 o;
        o.x = (sr[i]     - mu) * rstd * gv.x + bv.x;
        o.y = (sr[i + 1] - mu) * rstd * gv.y + bv.y;
        o.z = (sr[i + 2] - mu) * rstd * gv.z + bv.z;
        o.w = (sr[i + 3] - mu) * rstd * gv.w + bv.w;
        *(float4*)(out + row * 2048 + i) = o;
    }
}

// ----------------------------------------------------------------------------- launch
extern "C" void kernel_launch(void* const* d_in, const int* in_sizes, int n_in,
                              void* d_out, int out_size, void* d_ws, size_t ws_size,
                              hipStream_t stream) {
    const float* x     = (const float*)d_in[0];
    const float* Wq    = (const float*)d_in[1];
    const float* bq    = (const float*)d_in[2];
    const float* Wk    = (const float*)d_in[3];
    const float* bk    = (const float*)d_in[4];
    const float* Wv    = (const float*)d_in[5];
    const float* bv    = (const float*)d_in[6];
    const float* Wo    = (const float*)d_in[7];
    const float* bo    = (const float*)d_in[8];
    const float* gamma = (const float*)d_in[9];
    const float* beta  = (const float*)d_in[10];
    float* out = (float*)d_out;

    char* ws = (char*)d_ws;
    size_t off = 0;
    bf16_t* xb    = (bf16_t*)(ws + off); off += 16777216;   // 4096x2048 bf16
    bf16_t* WqkvT = (bf16_t*)(ws + off); off += 12582912;   // 3072x2048 bf16
    bf16_t* WoT   = (bf16_t*)(ws + off); off += 8388608;    // 2048x2048 bf16
    float*  qbias = (float*)(ws + off);  off += 12288;      // 3072 f32
    bf16_t* QKV   = (bf16_t*)(ws + off); off += 25165824;   // 4096x3072 bf16 (V third unused)
    bf16_t* Vt    = (bf16_t*)(ws + off); off += 4194304;    // 8x128x2048 bf16
    bf16_t* Cb    = (bf16_t*)(ws + off); off += 16777216;   // 4096x2048 bf16
    bf16_t* Yb    = (bf16_t*)(ws + off); off += 16777216;   // 4096x2048 bf16 (GELU'd)

    prep_kernel<<<18444, 256, 0, stream>>>(x, xb, bq, bk, bv, qbias,
                                           Wq, Wk, Wv, Wo, WqkvT, WoT);

    // QKV GEMM (BK=64): writes Q,K to QKV and V transposed to Vt
    gemm_kernel<false, true><<<dim3(24, 32), 256, 0, stream>>>(xb, WqkvT, qbias, QKV, Vt, M_, NQKV_, D_);
    attn_kernel<<<1024, 128, 0, stream>>>(QKV, Vt, Cb);
    gemm_kernel<true, false><<<dim3(16, 32), 256, 0, stream>>>(Cb, WoT, bo, Yb, nullptr, M_, D_, 2048);
    ln_kernel<<<M_, 256, 0, stream>>>(Yb, x, gamma, beta, out);
}